// Round 14
// baseline (50.675 us; speedup 1.0000x reference)
//
#include <hip/hip_runtime.h>

#define NUM_INPUT   256
#define NUM_OUTPUT  64
#define N_INTERNAL  1023
#define STAGED_NODES 31          // tree levels 0..4 staged in LDS (31 KB)
#define THREADS 512              // 8 waves; ~40KB LDS -> 4 blocks/CU
#define NBLOCKS 2048             // 2048 blk * 8 waves * 4 groups * 2 elems = 131072

// Sum-reduce across each 16-lane row using DPP row_ror (VALU pipe, no DS ops).
__device__ __forceinline__ float group16_reduce_add(float acc) {
    int t;
    t = __builtin_amdgcn_update_dpp(0, __float_as_int(acc), 0x121, 0xf, 0xf, true);
    acc += __int_as_float(t);
    t = __builtin_amdgcn_update_dpp(0, __float_as_int(acc), 0x122, 0xf, 0xf, true);
    acc += __int_as_float(t);
    t = __builtin_amdgcn_update_dpp(0, __float_as_int(acc), 0x124, 0xf, 0xf, true);
    acc += __int_as_float(t);
    t = __builtin_amdgcn_update_dpp(0, __float_as_int(acc), 0x128, 0xf, 0xf, true);
    acc += __int_as_float(t);
    return acc;
}

// Product-reduce across each 16-lane row.
__device__ __forceinline__ float group16_reduce_mul(float v) {
    int t;
    t = __builtin_amdgcn_update_dpp(0, __float_as_int(v), 0x121, 0xf, 0xf, true);
    v *= __int_as_float(t);
    t = __builtin_amdgcn_update_dpp(0, __float_as_int(v), 0x122, 0xf, 0xf, true);
    v *= __int_as_float(t);
    t = __builtin_amdgcn_update_dpp(0, __float_as_int(v), 0x124, 0xf, 0xf, true);
    v *= __int_as_float(t);
    t = __builtin_amdgcn_update_dpp(0, __float_as_int(v), 0x128, 0xf, 0xf, true);
    v *= __int_as_float(t);
    return v;
}

// Issue element E's x row into the named register set; pinned so the loads
// cannot sink to their uses (R11: proven held, -2.3us).
#define XISSUE(E, X0, X1, X2, X3)                                           \
    {                                                                       \
        const float4* xp_ = reinterpret_cast<const float4*>(                \
            x + (size_t)(gbase + 4 * (E)) * NUM_INPUT);                     \
        X0 = xp_[s]; X1 = xp_[16 + s]; X2 = xp_[32 + s]; X3 = xp_[48 + s];  \
        __builtin_amdgcn_sched_barrier(0);                                  \
    }

// LDS-level step: ds_read row, dot, record -|z| (sigmoid deferred), descend.
#define LSTEP(IDX, ZND, X0, X1, X2, X3)                                     \
    {                                                                       \
        float a_i = lds_a[IDX];                                             \
        float b_i = lds_b[IDX];                                             \
        const float4* wr_ = reinterpret_cast<const float4*>(                \
            lds_w + (size_t)(IDX) * NUM_INPUT);                             \
        float4 w0 = wr_[s], w1 = wr_[16 + s], w2 = wr_[32 + s], w3 = wr_[48 + s]; \
        float a0 = X0.x * w0.x, a1 = X1.x * w1.x;                           \
        float a2 = X2.x * w2.x, a3 = X3.x * w3.x;                           \
        a0 = fmaf(X0.y, w0.y, a0); a1 = fmaf(X1.y, w1.y, a1);               \
        a2 = fmaf(X2.y, w2.y, a2); a3 = fmaf(X3.y, w3.y, a3);               \
        a0 = fmaf(X0.z, w0.z, a0); a1 = fmaf(X1.z, w1.z, a1);               \
        a2 = fmaf(X2.z, w2.z, a2); a3 = fmaf(X3.z, w3.z, a3);               \
        a0 = fmaf(X0.w, w0.w, a0); a1 = fmaf(X1.w, w1.w, a1);               \
        a2 = fmaf(X2.w, w2.w, a2); a3 = fmaf(X3.w, w3.w, a3);               \
        float acc_ = group16_reduce_add((a0 + a1) + (a2 + a3));             \
        float z = a_i * (acc_ + b_i);                                       \
        ZND = __int_as_float(__float_as_int(z) | 0x80000000);               \
        IDX = 2 * (IDX) + 1 + ((z >= 0.0f) ? 1 : 0);                        \
    }

// Deep-step halves for chain A (registers wa0..wa3) and chain B (wb0..wb3).
#define DISSUE_A(IDX)                                                       \
    {                                                                       \
        const float4* wr_ = reinterpret_cast<const float4*>(                \
            W + (size_t)(IDX) * NUM_INPUT);                                 \
        wa0 = wr_[s]; wa1 = wr_[16 + s]; wa2 = wr_[32 + s]; wa3 = wr_[48 + s]; \
    }
#define DISSUE_B(IDX)                                                       \
    {                                                                       \
        const float4* wr_ = reinterpret_cast<const float4*>(                \
            W + (size_t)(IDX) * NUM_INPUT);                                 \
        wb0 = wr_[s]; wb1 = wr_[16 + s]; wb2 = wr_[32 + s]; wb3 = wr_[48 + s]; \
    }
#define DCONSUME_A(IDX, ZND, X0, X1, X2, X3)                                \
    {                                                                       \
        float a_i = lds_a[IDX];                                             \
        float b_i = lds_b[IDX];                                             \
        float a0 = X0.x * wa0.x, a1 = X1.x * wa1.x;                         \
        float a2 = X2.x * wa2.x, a3 = X3.x * wa3.x;                         \
        a0 = fmaf(X0.y, wa0.y, a0); a1 = fmaf(X1.y, wa1.y, a1);             \
        a2 = fmaf(X2.y, wa2.y, a2); a3 = fmaf(X3.y, wa3.y, a3);             \
        a0 = fmaf(X0.z, wa0.z, a0); a1 = fmaf(X1.z, wa1.z, a1);             \
        a2 = fmaf(X2.z, wa2.z, a2); a3 = fmaf(X3.z, wa3.z, a3);             \
        a0 = fmaf(X0.w, wa0.w, a0); a1 = fmaf(X1.w, wa1.w, a1);             \
        a2 = fmaf(X2.w, wa2.w, a2); a3 = fmaf(X3.w, wa3.w, a3);             \
        float acc_ = group16_reduce_add((a0 + a1) + (a2 + a3));             \
        float z = a_i * (acc_ + b_i);                                       \
        ZND = __int_as_float(__float_as_int(z) | 0x80000000);               \
        IDX = 2 * (IDX) + 1 + ((z >= 0.0f) ? 1 : 0);                        \
    }
#define DCONSUME_B(IDX, ZND, X0, X1, X2, X3)                                \
    {                                                                       \
        float a_i = lds_a[IDX];                                             \
        float b_i = lds_b[IDX];                                             \
        float a0 = X0.x * wb0.x, a1 = X1.x * wb1.x;                         \
        float a2 = X2.x * wb2.x, a3 = X3.x * wb3.x;                         \
        a0 = fmaf(X0.y, wb0.y, a0); a1 = fmaf(X1.y, wb1.y, a1);             \
        a2 = fmaf(X2.y, wb2.y, a2); a3 = fmaf(X3.y, wb3.y, a3);             \
        a0 = fmaf(X0.z, wb0.z, a0); a1 = fmaf(X1.z, wb1.z, a1);             \
        a2 = fmaf(X2.z, wb2.z, a2); a3 = fmaf(X3.z, wb3.z, a3);             \
        a0 = fmaf(X0.w, wb0.w, a0); a1 = fmaf(X1.w, wb1.w, a1);             \
        a2 = fmaf(X2.w, wb2.w, a2); a3 = fmaf(X3.w, wb3.w, a3);             \
        float acc_ = group16_reduce_add((a0 + a1) + (a2 + a3));             \
        float z = a_i * (acc_ + b_i);                                       \
        ZND = __int_as_float(__float_as_int(z) | 0x80000000);               \
        IDX = 2 * (IDX) + 1 + ((z >= 0.0f) ? 1 : 0);                        \
    }

// Deferred-sigmoid epilogue + leaf multiply + store for element E.
#define EPI(E, IDX, Z0, Z1, Z2, Z3, Z4, Z5, Z6, Z7, Z8, Z9)                 \
    {                                                                       \
        float zsel = -1e30f;                                                \
        zsel = (s == 0) ? Z0 : zsel; zsel = (s == 1) ? Z1 : zsel;           \
        zsel = (s == 2) ? Z2 : zsel; zsel = (s == 3) ? Z3 : zsel;           \
        zsel = (s == 4) ? Z4 : zsel; zsel = (s == 5) ? Z5 : zsel;           \
        zsel = (s == 6) ? Z6 : zsel; zsel = (s == 7) ? Z7 : zsel;           \
        zsel = (s == 8) ? Z8 : zsel; zsel = (s == 9) ? Z9 : zsel;           \
        float f = 1.0f + __expf(zsel);                                      \
        float p = group16_reduce_mul(f);                                    \
        float mult = 1.0f / p;                                              \
        const int leaf = (IDX) - N_INTERNAL;                                \
        const float4 lv = reinterpret_cast<const float4*>(                  \
            leaves + (size_t)leaf * NUM_OUTPUT)[s];                         \
        float4 o;                                                           \
        o.x = mult * lv.x; o.y = mult * lv.y;                               \
        o.z = mult * lv.z; o.w = mult * lv.w;                               \
        reinterpret_cast<float4*>(                                          \
            out + (size_t)(gbase + 4 * (E)) * NUM_OUTPUT)[s] = o;           \
    }

__global__ __launch_bounds__(THREADS, 4) void ogtree_kernel(
    const float* __restrict__ x,
    const float* __restrict__ W,
    const float* __restrict__ b,
    const float* __restrict__ alpha,
    const float* __restrict__ leaves,
    float* __restrict__ out)
{
    __shared__ float lds_w[STAGED_NODES * NUM_INPUT];  // 31 KB
    __shared__ float lds_b[N_INTERNAL];                // 4 KB
    __shared__ float lds_a[N_INTERNAL];                // 4 KB

    const int tid  = threadIdx.x;
    const int lane = tid & 63;
    const int wid  = tid >> 6;
    const int g    = lane >> 4;   // element group within wave (0..3)
    const int s    = lane & 15;   // sub-lane within group
    // group's elements: gbase + 4*e, e in {0,1} (wave reads 4 consecutive
    // element rows per x-load = contiguous 1KB -> coalesced)
    const int gbase = blockIdx.x * (THREADS / 64) * 8 + wid * 8 + g;

    float4 xa0, xa1, xa2, xa3;    // element 0's x
    float4 xb0, xb1, xb2, xb3;    // element 1's x
    float4 wa0, wa1, wa2, wa3;    // chain A in-flight deep W fragment
    float4 wb0, wb1, wb2, wb3;    // chain B in-flight deep W fragment

    // ---- element 0's x issued BEFORE staging: latency hides under stage ----
    XISSUE(0, xa0, xa1, xa2, xa3)

    // ---- stage W levels 0..4 (rows 0..30) + all b/alpha ----
    {
        const float4* Wv = reinterpret_cast<const float4*>(W);
        float4* lw4 = reinterpret_cast<float4*>(lds_w);
        #pragma unroll
        for (int i = tid; i < STAGED_NODES * NUM_INPUT / 4; i += THREADS)
            lw4[i] = Wv[i];
        for (int i = tid; i < N_INTERNAL; i += THREADS) {
            lds_b[i] = b[i];
            lds_a[i] = alpha[i];
        }
    }
    __syncthreads();

    // element 1's x: issued now, covered by element 0's entire LDS phase
    XISSUE(1, xb0, xb1, xb2, xb3)

    int idxA = 0, idxB = 0;
    float ZA0, ZA1, ZA2, ZA3, ZA4, ZA5, ZA6, ZA7, ZA8, ZA9;
    float ZB0, ZB1, ZB2, ZB3, ZB4, ZB5, ZB6, ZB7, ZB8, ZB9;

    // ---- LDS phases, serial (cheap ~120cy links, DS pipe) ----
    LSTEP(idxA, ZA0, xa0, xa1, xa2, xa3)
    LSTEP(idxA, ZA1, xa0, xa1, xa2, xa3)
    LSTEP(idxA, ZA2, xa0, xa1, xa2, xa3)
    LSTEP(idxA, ZA3, xa0, xa1, xa2, xa3)
    LSTEP(idxA, ZA4, xa0, xa1, xa2, xa3)
    LSTEP(idxB, ZB0, xb0, xb1, xb2, xb3)
    LSTEP(idxB, ZB1, xb0, xb1, xb2, xb3)
    LSTEP(idxB, ZB2, xb0, xb1, xb2, xb3)
    LSTEP(idxB, ZB3, xb0, xb1, xb2, xb3)
    LSTEP(idxB, ZB4, xb0, xb1, xb2, xb3)

    // ---- dual-chain deep phase: levels 5..9 of BOTH elements interleaved.
    // Two independent gather chains; while A waits on L2, B consumes+issues.
    DISSUE_A(idxA)
    DISSUE_B(idxB)
    // level 5
    DCONSUME_A(idxA, ZA5, xa0, xa1, xa2, xa3)
    DISSUE_A(idxA)
    DCONSUME_B(idxB, ZB5, xb0, xb1, xb2, xb3)
    DISSUE_B(idxB)
    // level 6
    DCONSUME_A(idxA, ZA6, xa0, xa1, xa2, xa3)
    DISSUE_A(idxA)
    DCONSUME_B(idxB, ZB6, xb0, xb1, xb2, xb3)
    DISSUE_B(idxB)
    // level 7
    DCONSUME_A(idxA, ZA7, xa0, xa1, xa2, xa3)
    DISSUE_A(idxA)
    DCONSUME_B(idxB, ZB7, xb0, xb1, xb2, xb3)
    DISSUE_B(idxB)
    // level 8
    DCONSUME_A(idxA, ZA8, xa0, xa1, xa2, xa3)
    DISSUE_A(idxA)
    DCONSUME_B(idxB, ZB8, xb0, xb1, xb2, xb3)
    DISSUE_B(idxB)
    // level 9
    DCONSUME_A(idxA, ZA9, xa0, xa1, xa2, xa3)
    DCONSUME_B(idxB, ZB9, xb0, xb1, xb2, xb3)

    // ---- epilogues ----
    EPI(0, idxA, ZA0, ZA1, ZA2, ZA3, ZA4, ZA5, ZA6, ZA7, ZA8, ZA9)
    EPI(1, idxB, ZB0, ZB1, ZB2, ZB3, ZB4, ZB5, ZB6, ZB7, ZB8, ZB9)
}

extern "C" void kernel_launch(void* const* d_in, const int* in_sizes, int n_in,
                              void* d_out, int out_size, void* d_ws, size_t ws_size,
                              hipStream_t stream) {
    const float* x      = (const float*)d_in[0];
    const float* W      = (const float*)d_in[1];
    const float* b      = (const float*)d_in[2];
    const float* alpha  = (const float*)d_in[3];
    const float* leaves = (const float*)d_in[4];
    float* out = (float*)d_out;

    ogtree_kernel<<<NBLOCKS, THREADS, 0, stream>>>(x, W, b, alpha, leaves, out);
}

// Round 15
// 47.209 us; speedup vs baseline: 1.0734x; 1.0734x over previous
//
#include <hip/hip_runtime.h>

#define NUM_INPUT   256
#define NUM_OUTPUT  64
#define MAX_DEPTH   10
#define N_INTERNAL  1023
#define STAGED_NODES 31          // tree levels 0..4 staged in LDS (31 KB)
#define THREADS 512              // 8 waves
#define NBLOCKS 1024
#define ELEMS_PER_GROUP 4        // sequential, software-pipelined x prefetch

// Sum-reduce across each 16-lane row using DPP row_ror (VALU pipe, no DS ops).
__device__ __forceinline__ float group16_reduce_add(float acc) {
    int t;
    t = __builtin_amdgcn_update_dpp(0, __float_as_int(acc), 0x121, 0xf, 0xf, true);
    acc += __int_as_float(t);
    t = __builtin_amdgcn_update_dpp(0, __float_as_int(acc), 0x122, 0xf, 0xf, true);
    acc += __int_as_float(t);
    t = __builtin_amdgcn_update_dpp(0, __float_as_int(acc), 0x124, 0xf, 0xf, true);
    acc += __int_as_float(t);
    t = __builtin_amdgcn_update_dpp(0, __float_as_int(acc), 0x128, 0xf, 0xf, true);
    acc += __int_as_float(t);
    return acc;
}

// Product-reduce across each 16-lane row.
__device__ __forceinline__ float group16_reduce_mul(float v) {
    int t;
    t = __builtin_amdgcn_update_dpp(0, __float_as_int(v), 0x121, 0xf, 0xf, true);
    v *= __int_as_float(t);
    t = __builtin_amdgcn_update_dpp(0, __float_as_int(v), 0x122, 0xf, 0xf, true);
    v *= __int_as_float(t);
    t = __builtin_amdgcn_update_dpp(0, __float_as_int(v), 0x124, 0xf, 0xf, true);
    v *= __int_as_float(t);
    t = __builtin_amdgcn_update_dpp(0, __float_as_int(v), 0x128, 0xf, 0xf, true);
    v *= __int_as_float(t);
    return v;
}

// One depth step with explicit x-register set; records -|z| (sigmoid deferred).
#define STEP_X(BASE, IDX, ZND, X0, X1, X2, X3)                              \
    {                                                                       \
        float a_i = lds_a[IDX];                                             \
        float b_i = lds_b[IDX];                                             \
        const float4* wr_ = reinterpret_cast<const float4*>(                \
            (BASE) + (size_t)(IDX) * NUM_INPUT);                            \
        float4 w0 = wr_[s], w1 = wr_[16 + s], w2 = wr_[32 + s], w3 = wr_[48 + s]; \
        float a0 = X0.x * w0.x, a1 = X1.x * w1.x;                           \
        float a2 = X2.x * w2.x, a3 = X3.x * w3.x;                           \
        a0 = fmaf(X0.y, w0.y, a0); a1 = fmaf(X1.y, w1.y, a1);               \
        a2 = fmaf(X2.y, w2.y, a2); a3 = fmaf(X3.y, w3.y, a3);               \
        a0 = fmaf(X0.z, w0.z, a0); a1 = fmaf(X1.z, w1.z, a1);               \
        a2 = fmaf(X2.z, w2.z, a2); a3 = fmaf(X3.z, w3.z, a3);               \
        a0 = fmaf(X0.w, w0.w, a0); a1 = fmaf(X1.w, w1.w, a1);               \
        a2 = fmaf(X2.w, w2.w, a2); a3 = fmaf(X3.w, w3.w, a3);               \
        float acc_ = group16_reduce_add((a0 + a1) + (a2 + a3));             \
        float z = a_i * (acc_ + b_i);                                       \
        ZND = __int_as_float(__float_as_int(z) | 0x80000000);               \
        IDX = 2 * (IDX) + 1 + ((z >= 0.0f) ? 1 : 0);                        \
    }

// Full traversal of one element using x set XC; optionally prefetch the NEXT
// element's x into set XN during this element's deep phase (pinned so the
// compiler cannot sink the loads — R4/R9 showed it otherwise will).
#define ONE_ELEM(E, XC0, XC1, XC2, XC3, XN0, XN1, XN2, XN3, PF)             \
    {                                                                       \
        int idx = 0;                                                        \
        float zn0, zn1, zn2, zn3, zn4, zn5, zn6, zn7, zn8, zn9;             \
        /* depths 0..4 from LDS (DS pipe) */                                \
        STEP_X(lds_w, idx, zn0, XC0, XC1, XC2, XC3)                         \
        STEP_X(lds_w, idx, zn1, XC0, XC1, XC2, XC3)                         \
        STEP_X(lds_w, idx, zn2, XC0, XC1, XC2, XC3)                         \
        STEP_X(lds_w, idx, zn3, XC0, XC1, XC2, XC3)                         \
        STEP_X(lds_w, idx, zn4, XC0, XC1, XC2, XC3)                         \
        if (PF) {                                                           \
            const float4* xp_ = reinterpret_cast<const float4*>(            \
                x + (size_t)(gbase + 4 * ((E) + 1)) * NUM_INPUT);           \
            XN0 = xp_[s];      XN1 = xp_[16 + s];                           \
            XN2 = xp_[32 + s]; XN3 = xp_[48 + s];                           \
            __builtin_amdgcn_sched_barrier(0);                              \
        }                                                                   \
        /* depths 5..9 gathered from global (L2) — covers the prefetch */   \
        STEP_X(W, idx, zn5, XC0, XC1, XC2, XC3)                             \
        STEP_X(W, idx, zn6, XC0, XC1, XC2, XC3)                             \
        STEP_X(W, idx, zn7, XC0, XC1, XC2, XC3)                             \
        STEP_X(W, idx, zn8, XC0, XC1, XC2, XC3)                             \
        STEP_X(W, idx, zn9, XC0, XC1, XC2, XC3)                             \
        /* deferred sigmoid: mult = 1 / prod_d (1 + exp(-|z_d|)) */         \
        float zsel = -1e30f;                                                \
        zsel = (s == 0) ? zn0 : zsel; zsel = (s == 1) ? zn1 : zsel;         \
        zsel = (s == 2) ? zn2 : zsel; zsel = (s == 3) ? zn3 : zsel;         \
        zsel = (s == 4) ? zn4 : zsel; zsel = (s == 5) ? zn5 : zsel;         \
        zsel = (s == 6) ? zn6 : zsel; zsel = (s == 7) ? zn7 : zsel;         \
        zsel = (s == 8) ? zn8 : zsel; zsel = (s == 9) ? zn9 : zsel;         \
        float f = 1.0f + __expf(zsel);                                      \
        float p = group16_reduce_mul(f);                                    \
        float mult = 1.0f / p;                                              \
        const int leaf = idx - N_INTERNAL;                                  \
        const float4 lv = reinterpret_cast<const float4*>(                  \
            leaves + (size_t)leaf * NUM_OUTPUT)[s];                         \
        float4 o;                                                           \
        o.x = mult * lv.x; o.y = mult * lv.y;                               \
        o.z = mult * lv.z; o.w = mult * lv.w;                               \
        reinterpret_cast<float4*>(                                          \
            out + (size_t)(gbase + 4 * (E)) * NUM_OUTPUT)[s] = o;           \
    }

__global__ __launch_bounds__(THREADS, 4) void ogtree_kernel(
    const float* __restrict__ x,
    const float* __restrict__ W,
    const float* __restrict__ b,
    const float* __restrict__ alpha,
    const float* __restrict__ leaves,
    float* __restrict__ out)
{
    __shared__ float lds_w[STAGED_NODES * NUM_INPUT];  // 31 KB
    __shared__ float lds_b[N_INTERNAL];                // 4 KB
    __shared__ float lds_a[N_INTERNAL];                // 4 KB

    const int tid  = threadIdx.x;
    const int lane = tid & 63;
    const int wid  = tid >> 6;
    const int g    = lane >> 4;   // element group within wave (0..3)
    const int s    = lane & 15;   // sub-lane within group
    // group's elements: gbase + 4*e, e = 0..3 (wave reads 4 consecutive
    // elements = contiguous 1KB at each round -> coalesced)
    const int gbase = blockIdx.x * (THREADS / 64) * 16 + wid * 16 + g;

    // ---- element 0's x issued BEFORE staging: latency hides under stage ----
    const float4* xp0 = reinterpret_cast<const float4*>(x + (size_t)gbase * NUM_INPUT);
    float4 xa0 = xp0[s], xa1 = xp0[16 + s], xa2 = xp0[32 + s], xa3 = xp0[48 + s];

    // ---- stage W levels 0..4 (rows 0..30) + all b/alpha ----
    {
        const float4* Wv = reinterpret_cast<const float4*>(W);
        float4* lw4 = reinterpret_cast<float4*>(lds_w);
        #pragma unroll
        for (int i = tid; i < STAGED_NODES * NUM_INPUT / 4; i += THREADS)
            lw4[i] = Wv[i];
        for (int i = tid; i < N_INTERNAL; i += THREADS) {
            lds_b[i] = b[i];
            lds_a[i] = alpha[i];
        }
    }
    __syncthreads();

    float4 xb0, xb1, xb2, xb3;   // ping-pong second x set

    // e=0: current in A, prefetch e=1 into B during deep phase
    ONE_ELEM(0, xa0, xa1, xa2, xa3, xb0, xb1, xb2, xb3, 1)
    // e=1: current in B, prefetch e=2 into A
    ONE_ELEM(1, xb0, xb1, xb2, xb3, xa0, xa1, xa2, xa3, 1)
    // e=2: current in A, prefetch e=3 into B
    ONE_ELEM(2, xa0, xa1, xa2, xa3, xb0, xb1, xb2, xb3, 1)
    // e=3: current in B, no prefetch
    ONE_ELEM(3, xb0, xb1, xb2, xb3, xa0, xa1, xa2, xa3, 0)
}

extern "C" void kernel_launch(void* const* d_in, const int* in_sizes, int n_in,
                              void* d_out, int out_size, void* d_ws, size_t ws_size,
                              hipStream_t stream) {
    const float* x      = (const float*)d_in[0];
    const float* W      = (const float*)d_in[1];
    const float* b      = (const float*)d_in[2];
    const float* alpha  = (const float*)d_in[3];
    const float* leaves = (const float*)d_in[4];
    float* out = (float*)d_out;

    // 1024 blocks * 8 waves * 4 groups * 4 elems = 131072
    ogtree_kernel<<<NBLOCKS, THREADS, 0, stream>>>(x, W, b, alpha, leaves, out);
}